// Round 1
// baseline (91.206 us; speedup 1.0000x reference)
//
#include <hip/hip_runtime.h>

// Soft histogram via quantization table:
//   hist[b,c,j] = (1/P) * sum_pixels f_j(x),  f_j(x) = k_j(x)/(sum_j k_j(x)+1e-12)
// f depends only on x -> quantize x into NQ cells, precompute f at cell centers,
// reduce to integer histogram + tiny contraction. Quantization error ~2e-6 << 3.3e-4 tol.

#define NQ      1024
#define NBINS   64
#define NIMG    24          // B*C = 8*3
#define IMG_PIX (512 * 512) // 262144 pixels per (b,c) image
#define BPI     32          // blocks per image in the count kernel

// ---- Stage 1: table[q][j] = normalized Gaussian kernel at quant-cell center q ----
__global__ __launch_bounds__(256) void soft_hist_table(
    const float* __restrict__ centers, float* __restrict__ table)
{
    const int t    = threadIdx.x;
    const int lane = t & 63;              // bin index (64 bins == 1 wave)
    const int q    = blockIdx.x * 4 + (t >> 6);
    const float cq = ((float)q + 0.5f) * (1.0f / (float)NQ);
    // (x - c) / (SIGMA + 1e-12); 0.02 + 1e-12 rounds to 0.02f in fp32
    const float d  = (cq - centers[lane]) * 50.0f;
    const float e  = expf(-0.5f * d * d);
    float s = e;
    #pragma unroll
    for (int off = 32; off > 0; off >>= 1) s += __shfl_xor(s, off, 64);
    table[q * NBINS + lane] = e / (s + 1e-12f);
}

// ---- Stage 2: per-image integer histogram over NQ quant cells ----
__global__ __launch_bounds__(256) void soft_hist_count(
    const float* __restrict__ x, unsigned int* __restrict__ tot)
{
    __shared__ unsigned int h[NQ];
    const int t   = threadIdx.x;
    const int img = blockIdx.x;
    const int s   = blockIdx.y;

    #pragma unroll
    for (int k = 0; k < NQ / 256; ++k) h[t + k * 256] = 0u;
    __syncthreads();

    // This block covers 2048 float4 (8192 pixels) of image `img`.
    const float4* x4 = (const float4*)x
                     + (size_t)img * (IMG_PIX / 4)
                     + (size_t)s * (IMG_PIX / 4 / BPI);

    // Prefetch all 8 float4 into registers first -> 8 loads in flight.
    float4 v[8];
    #pragma unroll
    for (int r = 0; r < 8; ++r) v[r] = x4[r * 256 + t];

    #pragma unroll
    for (int r = 0; r < 8; ++r) {
        const float4 p = v[r];
        int q0 = (int)(p.x * (float)NQ); q0 = q0 < 0 ? 0 : (q0 > NQ - 1 ? NQ - 1 : q0);
        int q1 = (int)(p.y * (float)NQ); q1 = q1 < 0 ? 0 : (q1 > NQ - 1 ? NQ - 1 : q1);
        int q2 = (int)(p.z * (float)NQ); q2 = q2 < 0 ? 0 : (q2 > NQ - 1 ? NQ - 1 : q2);
        int q3 = (int)(p.w * (float)NQ); q3 = q3 < 0 ? 0 : (q3 > NQ - 1 ? NQ - 1 : q3);
        atomicAdd(&h[q0], 1u);
        atomicAdd(&h[q1], 1u);
        atomicAdd(&h[q2], 1u);
        atomicAdd(&h[q3], 1u);
    }
    __syncthreads();

    unsigned int* dst = tot + (size_t)img * NQ;
    #pragma unroll
    for (int k = 0; k < NQ / 256; ++k) {
        const int q = t + k * 256;
        const unsigned int c = h[q];
        if (c) atomicAdd(&dst[q], c);
    }
}

// ---- Stage 3: hist[j] = sum_q tot[q]*table[q][j]; /P; normalize over bins ----
__global__ __launch_bounds__(256) void soft_hist_final(
    const unsigned int* __restrict__ tot, const float* __restrict__ table,
    float* __restrict__ out)
{
    __shared__ float tf[NQ];
    __shared__ float part[4][NBINS];
    const int t   = threadIdx.x;
    const int img = blockIdx.x;

    const unsigned int* src = tot + (size_t)img * NQ;
    #pragma unroll
    for (int k = 0; k < NQ / 256; ++k) tf[t + k * 256] = (float)src[t + k * 256];
    __syncthreads();

    const int j = t & 63;      // bin
    const int g = t >> 6;      // q-group (4 groups of NQ/4)
    const int Q4 = NQ / 4;
    float acc = 0.0f;
    const float* tb = table + (size_t)(g * Q4) * NBINS + j;
    #pragma unroll 4
    for (int qq = 0; qq < Q4; ++qq)
        acc += tb[(size_t)qq * NBINS] * tf[g * Q4 + qq];  // coalesced 256B table reads
    part[g][j] = acc;
    __syncthreads();

    if (t < 64) {
        const float hsum = part[0][t] + part[1][t] + part[2][t] + part[3][t];
        const float hm   = hsum * (1.0f / (float)IMG_PIX);   // mean over pixels
        float ss = hm;
        #pragma unroll
        for (int off = 32; off > 0; off >>= 1) ss += __shfl_xor(ss, off, 64);
        out[img * NBINS + t] = hm / (ss + 1e-12f);           // per-image normalize
    }
}

extern "C" void kernel_launch(void* const* d_in, const int* in_sizes, int n_in,
                              void* d_out, int out_size, void* d_ws, size_t ws_size,
                              hipStream_t stream)
{
    const float* x       = (const float*)d_in[0];   // (8,3,512,512) fp32
    const float* centers = (const float*)d_in[1];   // (64,) fp32
    float* out           = (float*)d_out;           // (8,3,64) fp32

    float*        table = (float*)d_ws;                                   // 256 KB
    unsigned int* tot   = (unsigned int*)((char*)d_ws + (size_t)NQ * NBINS * sizeof(float)); // 96 KB

    hipMemsetAsync(tot, 0, (size_t)NIMG * NQ * sizeof(unsigned int), stream);
    soft_hist_table<<<NQ / 4, 256, 0, stream>>>(centers, table);
    soft_hist_count<<<dim3(NIMG, BPI), 256, 0, stream>>>(x, tot);
    soft_hist_final<<<NIMG, 256, 0, stream>>>(tot, table, out);
}

// Round 2
// 88.867 us; speedup vs baseline: 1.0263x; 1.0263x over previous
//
#include <hip/hip_runtime.h>

// Soft histogram via quantization table:
//   hist[b,c,j] = (1/P) * sum_pixels f_j(x),  f_j(x) = k_j(x)/(sum_j k_j(x)+1e-12)
// f depends only on x -> quantize x into NQ cells, precompute f at cell centers,
// reduce to integer histogram + tiny contraction. Measured absmax 1.2e-4 vs 3.3e-4 tol.
//
// R2: two dispatches total. Count blocks store disjoint partial histograms
// (no global atomics, no zero-init memset); table blocks ride along in the
// same grid. Finalize kernel sums partials + contracts against the table.

#define NQ      1024
#define NBINS   64
#define NIMG    24            // B*C = 8*3
#define IMG_PIX (512 * 512)   // 262144 pixels per (b,c) image
#define BPI     32            // count blocks per image
#define CNT_BLOCKS (NIMG * BPI)        // 768
#define TBL_BLOCKS (NQ / 4)            // 256 (4 quant cells per 256-thread block)

// ---- K1: fused count (blocks 0..767) + table build (blocks 768..1023) ----
__global__ __launch_bounds__(256) void soft_hist_k1(
    const float* __restrict__ x, const float* __restrict__ centers,
    float* __restrict__ table, unsigned int* __restrict__ parts)
{
    const int bid = blockIdx.x;
    const int t   = threadIdx.x;

    if (bid < CNT_BLOCKS) {
        // ---- per-(image,slice) histogram over NQ quant cells ----
        __shared__ unsigned int h[NQ];
        #pragma unroll
        for (int k = 0; k < NQ / 256; ++k) h[t + k * 256] = 0u;
        __syncthreads();

        // Block covers 2048 float4 (8192 pixels), contiguous 32 KB chunk.
        const float4* x4 = (const float4*)x + (size_t)bid * (IMG_PIX / 4 / BPI);

        // Prefetch all 8 float4 into registers -> 8 HBM loads in flight.
        float4 v[8];
        #pragma unroll
        for (int r = 0; r < 8; ++r) v[r] = x4[r * 256 + t];

        #pragma unroll
        for (int r = 0; r < 8; ++r) {
            const float4 p = v[r];
            int q0 = (int)(p.x * (float)NQ); q0 = q0 < 0 ? 0 : (q0 > NQ - 1 ? NQ - 1 : q0);
            int q1 = (int)(p.y * (float)NQ); q1 = q1 < 0 ? 0 : (q1 > NQ - 1 ? NQ - 1 : q1);
            int q2 = (int)(p.z * (float)NQ); q2 = q2 < 0 ? 0 : (q2 > NQ - 1 ? NQ - 1 : q2);
            int q3 = (int)(p.w * (float)NQ); q3 = q3 < 0 ? 0 : (q3 > NQ - 1 ? NQ - 1 : q3);
            atomicAdd(&h[q0], 1u);
            atomicAdd(&h[q1], 1u);
            atomicAdd(&h[q2], 1u);
            atomicAdd(&h[q3], 1u);
        }
        __syncthreads();

        // Plain coalesced store of this block's partial histogram (disjoint slot).
        unsigned int* dst = parts + (size_t)bid * NQ;
        #pragma unroll
        for (int k = 0; k < NQ / 256; ++k) dst[t + k * 256] = h[t + k * 256];
    } else {
        // ---- table[q][j] = normalized Gaussian kernel at quant-cell center q ----
        const int lane = t & 63;                       // bin (64 bins == 1 wave)
        const int q    = (bid - CNT_BLOCKS) * 4 + (t >> 6);
        const float cq = ((float)q + 0.5f) * (1.0f / (float)NQ);
        // (x - c)/(SIGMA + 1e-12); 0.02 + 1e-12 rounds to 0.02f in fp32
        const float d  = (cq - centers[lane]) * 50.0f;
        const float e  = expf(-0.5f * d * d);
        float s = e;
        #pragma unroll
        for (int off = 32; off > 0; off >>= 1) s += __shfl_xor(s, off, 64);
        table[q * NBINS + lane] = e / (s + 1e-12f);
    }
}

// ---- K2: sum partials; hist[j] = sum_q tot[q]*table[q][j]; /P; normalize ----
__global__ __launch_bounds__(256) void soft_hist_final(
    const unsigned int* __restrict__ parts, const float* __restrict__ table,
    float* __restrict__ out)
{
    __shared__ float tf[NQ];
    __shared__ float part[4][NBINS];
    const int t   = threadIdx.x;
    const int img = blockIdx.x;

    // Sum this image's 32 partial histograms (coalesced across t per slice).
    const unsigned int* src = parts + (size_t)img * BPI * NQ;
    #pragma unroll
    for (int k = 0; k < NQ / 256; ++k) {
        const int q = t + k * 256;
        unsigned int s = 0;
        #pragma unroll 8
        for (int b = 0; b < BPI; ++b) s += src[(size_t)b * NQ + q];
        tf[q] = (float)s;
    }
    __syncthreads();

    const int j  = t & 63;     // bin
    const int g  = t >> 6;     // q-group (4 groups of NQ/4)
    const int Q4 = NQ / 4;
    float acc = 0.0f;
    const float* tb = table + (size_t)(g * Q4) * NBINS + j;
    #pragma unroll 4
    for (int qq = 0; qq < Q4; ++qq)
        acc += tb[(size_t)qq * NBINS] * tf[g * Q4 + qq];   // coalesced 256B table reads
    part[g][j] = acc;
    __syncthreads();

    if (t < 64) {
        const float hsum = part[0][t] + part[1][t] + part[2][t] + part[3][t];
        const float hm   = hsum * (1.0f / (float)IMG_PIX);   // mean over pixels
        float ss = hm;
        #pragma unroll
        for (int off = 32; off > 0; off >>= 1) ss += __shfl_xor(ss, off, 64);
        out[img * NBINS + t] = hm / (ss + 1e-12f);           // per-image normalize
    }
}

extern "C" void kernel_launch(void* const* d_in, const int* in_sizes, int n_in,
                              void* d_out, int out_size, void* d_ws, size_t ws_size,
                              hipStream_t stream)
{
    const float* x       = (const float*)d_in[0];   // (8,3,512,512) fp32
    const float* centers = (const float*)d_in[1];   // (64,) fp32
    float* out           = (float*)d_out;           // (8,3,64) fp32

    float*        table = (float*)d_ws;                                    // 256 KB
    unsigned int* parts = (unsigned int*)((char*)d_ws
                        + (size_t)NQ * NBINS * sizeof(float));             // 3 MB

    soft_hist_k1<<<CNT_BLOCKS + TBL_BLOCKS, 256, 0, stream>>>(x, centers, table, parts);
    soft_hist_final<<<NIMG, 256, 0, stream>>>(parts, table, out);
}